// Round 25
// baseline (239.635 us; speedup 1.0000x reference)
//
#include <hip/hip_runtime.h>
#include <hip/hip_fp16.h>

#define NN 100000
#define NE 1600000
// IN_FEAT=128, N_HEADS=8, OUT_FEAT=16, H*F=128

typedef __attribute__((ext_vector_type(2))) float f32x2;
typedef __attribute__((ext_vector_type(4))) float f32x4;
typedef __attribute__((ext_vector_type(8))) short short8x;   // 8 bf16 (4 VGPRs)

static __device__ __forceinline__ unsigned short f32_to_bf16_rne(float x) {
    unsigned int u = __float_as_uint(x);
    u += 0x7fff + ((u >> 16) & 1);   // round-to-nearest-even
    return (unsigned short)(u >> 16);
}
static __device__ __forceinline__ float bf16_to_f32(unsigned int bits16) {
    return __uint_as_float(bits16 << 16);
}

// ---------------- Kernel 1: MFMA proj-GEMM + attention scores ----------------
// x,W staged as bf16 in LDS (rows padded +8 to break 256B-stride bank conflicts).
// 4 waves x 16 rows; per wave: 8 N-tiles x 4 K-chunks of mfma_f32_16x16x32_bf16.
// C/D layout (m89-verified): col=lane&15, row=(lane>>4)*4+reg.
// projT8 fp8 e4m3 f-major: 8 heads per (row,feat) packed into ONE 8B store.
__global__ __launch_bounds__(256) void gemm_score_kernel(const float* __restrict__ x,
                                                         const float* __restrict__ W,
                                                         const float* __restrict__ a_src,
                                                         const float* __restrict__ a_tgt,
                                                         unsigned char* __restrict__ projT8,
                                                         unsigned short* __restrict__ s_src_b,
                                                         unsigned short* __restrict__ s_tgt_b) {
    __shared__ unsigned short sX[64][136];    // bf16, padded
    __shared__ unsigned short sWT[128][136];  // W transposed: sWT[col][k], bf16, padded
    const int t = threadIdx.x;
    const int n0 = blockIdx.x * 64;

    // stage x tile (64x128 f32 -> bf16): 2048 float4
#pragma unroll
    for (int p = 0; p < 8; p++) {
        int idx = t + p * 256;          // 0..2047
        int r = idx >> 5;               // 0..63
        int k4 = idx & 31;              // float4 index along k
        float4 v = make_float4(0.f, 0.f, 0.f, 0.f);
        int n = n0 + r;
        if (n < NN) v = *reinterpret_cast<const float4*>(&x[(size_t)n * 128 + k4 * 4]);
        ushort4 b;
        b.x = f32_to_bf16_rne(v.x); b.y = f32_to_bf16_rne(v.y);
        b.z = f32_to_bf16_rne(v.z); b.w = f32_to_bf16_rne(v.w);
        *reinterpret_cast<ushort4*>(&sX[r][k4 * 4]) = b;
    }
    // stage full W transposed (128x128 f32 -> bf16): 4096 float4
#pragma unroll
    for (int p = 0; p < 16; p++) {
        int idx = t + p * 256;          // 0..4095
        int kr = idx >> 5;              // 0..127
        int c4 = idx & 31;
        float4 v = *reinterpret_cast<const float4*>(&W[(size_t)kr * 128 + c4 * 4]);
        sWT[c4 * 4 + 0][kr] = f32_to_bf16_rne(v.x);
        sWT[c4 * 4 + 1][kr] = f32_to_bf16_rne(v.y);
        sWT[c4 * 4 + 2][kr] = f32_to_bf16_rne(v.z);
        sWT[c4 * 4 + 3][kr] = f32_to_bf16_rne(v.w);
    }
    __syncthreads();

    const int w = t >> 6;       // wave 0..3 -> rows w*16..w*16+15
    const int l = t & 63;
    const int f = l & 15;       // A row / B col within tile; also feature index
    const int kg = l >> 4;      // k-group 0..3

    // A fragments: lane holds A[row=f][k = kc*32 + kg*8 + i]
    short8x aF[4];
#pragma unroll
    for (int kc = 0; kc < 4; kc++)
        aF[kc] = *reinterpret_cast<const short8x*>(&sX[w * 16 + f][kc * 32 + kg * 8]);

    f32x4 acc[8];
#pragma unroll
    for (int nt = 0; nt < 8; nt++) acc[nt] = (f32x4){0.f, 0.f, 0.f, 0.f};

#pragma unroll
    for (int kc = 0; kc < 4; kc++) {
#pragma unroll
        for (int nt = 0; nt < 8; nt++) {
            // B fragment: lane holds B[k = kc*32 + kg*8 + i][col = nt*16 + f]
            short8x bF = *reinterpret_cast<const short8x*>(&sWT[nt * 16 + f][kc * 32 + kg * 8]);
            acc[nt] = __builtin_amdgcn_mfma_f32_16x16x32_bf16(aF[kc], bF, acc[nt], 0, 0, 0);
        }
    }

    // epilogue: col = nt*16 + f -> head = nt, feat = f; row = kg*4 + reg
    float aS[8], aT[8];
#pragma unroll
    for (int nt = 0; nt < 8; nt++) {
        aS[nt] = a_src[nt * 16 + f];
        aT[nt] = a_tgt[nt * 16 + f];
    }
#pragma unroll
    for (int reg = 0; reg < 4; reg++) {
        int n = n0 + w * 16 + kg * 4 + reg;
        bool valid = (n < NN);
        unsigned int p01 = __builtin_amdgcn_cvt_pk_fp8_f32(acc[0][reg], acc[1][reg], 0, false);
        unsigned int p23 = __builtin_amdgcn_cvt_pk_fp8_f32(acc[2][reg], acc[3][reg], 0, false);
        unsigned int p45 = __builtin_amdgcn_cvt_pk_fp8_f32(acc[4][reg], acc[5][reg], 0, false);
        unsigned int p67 = __builtin_amdgcn_cvt_pk_fp8_f32(acc[6][reg], acc[7][reg], 0, false);
        uint2 st8 = make_uint2((p01 & 0xFFFFu) | (p23 << 16), (p45 & 0xFFFFu) | (p67 << 16));
        if (valid) *reinterpret_cast<uint2*>(&projT8[(size_t)n * 128 + f * 8]) = st8;
#pragma unroll
        for (int nt = 0; nt < 8; nt++) {
            float psS = acc[nt][reg] * aS[nt];
            float psT = acc[nt][reg] * aT[nt];
            psS += __shfl_xor(psS, 1); psS += __shfl_xor(psS, 2);
            psS += __shfl_xor(psS, 4); psS += __shfl_xor(psS, 8);
            psT += __shfl_xor(psT, 1); psT += __shfl_xor(psT, 2);
            psT += __shfl_xor(psT, 4); psT += __shfl_xor(psT, 8);
            if (valid && f == 0) {
                s_src_b[(size_t)n * 8 + nt] = f32_to_bf16_rne(psS);
                s_tgt_b[(size_t)n * 8 + nt] = f32_to_bf16_rne(psT);
            }
        }
    }
}

// ---------------- Kernel 2: denom via packed-f16 HW atomics (frozen from r18/r24) ----------------
__global__ __launch_bounds__(256) void denom_kernel(const int* __restrict__ src,
                                                    const int* __restrict__ tgt,
                                                    const unsigned short* __restrict__ s_src_b,
                                                    const unsigned short* __restrict__ s_tgt_b,
                                                    __half* __restrict__ denom_h,
                                                    unsigned short* __restrict__ exb) {
    int gid = blockIdx.x * blockDim.x + threadIdx.x;
    int e = gid >> 2;
    if (e >= NE) return;
    int h0 = (gid & 3) * 2;
    int s = src[e], t = tgt[e];
    unsigned int ssp = *reinterpret_cast<const unsigned int*>(&s_src_b[(size_t)s * 8 + h0]);
    unsigned int stp = *reinterpret_cast<const unsigned int*>(&s_tgt_b[(size_t)t * 8 + h0]);
    float v0 = bf16_to_f32(ssp & 0xffffu) + bf16_to_f32(stp & 0xffffu);
    float v1 = bf16_to_f32(ssp >> 16) + bf16_to_f32(stp >> 16);
    v0 = v0 >= 0.f ? v0 : 0.2f * v0;
    v1 = v1 >= 0.f ? v1 : 0.2f * v1;
    float ex0 = expf(v0), ex1 = expf(v1);
    unsigned int pk = (unsigned int)f32_to_bf16_rne(ex0) | ((unsigned int)f32_to_bf16_rne(ex1) << 16);
    *reinterpret_cast<unsigned int*>(&exb[(size_t)e * 8 + h0]) = pk;
    unsafeAtomicAdd(reinterpret_cast<__half2*>(&denom_h[(size_t)t * 8 + h0]),
                    __floats2half2_rn(ex0, ex1));
}

// ---------------- Kernel 3: aggregate — fp8 gather + HW fp8 decode (frozen from r24) ----------------
__global__ __launch_bounds__(256) void aggregate_kernel(const int* __restrict__ src,
                                                        const int* __restrict__ tgt,
                                                        const __half* __restrict__ denom_h,
                                                        const unsigned short* __restrict__ exb,
                                                        const unsigned char* __restrict__ projT8,
                                                        __half* __restrict__ out_h) {
    int gid = blockIdx.x * blockDim.x + threadIdx.x;
    int e = gid >> 3;
    if (e >= NE) return;
    int j = gid & 7;       // head j; features 2j, 2j+1
    int s = src[e], t = tgt[e];
    float ex = bf16_to_f32(exb[(size_t)e * 8 + j]);
    float dj = __half2float(denom_h[(size_t)t * 8 + j]);
    float alpha = ex / (dj + 1e-16f);
    uint4 v = *reinterpret_cast<const uint4*>(&projT8[(size_t)s * 128 + j * 16]);
    f32x2 a01 = __builtin_amdgcn_cvt_pk_f32_fp8(v.x, false);
    f32x2 a23 = __builtin_amdgcn_cvt_pk_f32_fp8(v.x, true);
    f32x2 a45 = __builtin_amdgcn_cvt_pk_f32_fp8(v.y, false);
    f32x2 a67 = __builtin_amdgcn_cvt_pk_f32_fp8(v.y, true);
    f32x2 b01 = __builtin_amdgcn_cvt_pk_f32_fp8(v.z, false);
    f32x2 b23 = __builtin_amdgcn_cvt_pk_f32_fp8(v.z, true);
    f32x2 b45 = __builtin_amdgcn_cvt_pk_f32_fp8(v.w, false);
    f32x2 b67 = __builtin_amdgcn_cvt_pk_f32_fp8(v.w, true);
    float pa[8] = {a01.x, a01.y, a23.x, a23.y, a45.x, a45.y, a67.x, a67.y};
    float pb[8] = {b01.x, b01.y, b23.x, b23.y, b45.x, b45.y, b67.x, b67.y};
    float m0 = 0.f, m1 = 0.f;
#pragma unroll
    for (int k = 0; k < 8; k++) {
        float ak = __shfl(alpha, k, 8);
        m0 += ak * pa[k];
        m1 += ak * pb[k];
    }
    unsafeAtomicAdd(reinterpret_cast<__half2*>(&out_h[(size_t)t * 16 + 2 * j]),
                    __floats2half2_rn(m0 * 0.125f, m1 * 0.125f));
}

// ---------------- Kernel 4: bias + softmax over 16 features ----------------
__global__ __launch_bounds__(256) void softmax_kernel(const __half* __restrict__ out_h,
                                                      const float* __restrict__ bias,
                                                      float* __restrict__ out) {
    int gid = blockIdx.x * blockDim.x + threadIdx.x;
    int n = gid >> 4;
    int lane = gid & 15;
    if (n >= NN) return;
    float v = __half2float(out_h[(size_t)n * 16 + lane]) + bias[lane];
    float mx = v;
#pragma unroll
    for (int m = 1; m < 16; m <<= 1) mx = fmaxf(mx, __shfl_xor(mx, m, 64));
    float ex = expf(v - mx);
    float sum = ex;
#pragma unroll
    for (int m = 1; m < 16; m <<= 1) sum += __shfl_xor(sum, m, 64);
    out[(size_t)n * 16 + lane] = ex / sum;
}

extern "C" void kernel_launch(void* const* d_in, const int* in_sizes, int n_in,
                              void* d_out, int out_size, void* d_ws, size_t ws_size,
                              hipStream_t stream) {
    const float* x     = (const float*)d_in[0];
    const int*   ei    = (const int*)d_in[1];
    const float* W     = (const float*)d_in[2];
    const float* a_src = (const float*)d_in[3];
    const float* a_tgt = (const float*)d_in[4];
    const float* bias  = (const float*)d_in[5];
    float* out = (float*)d_out;

    const int* src = ei;            // edge_index[0]
    const int* tgt = ei + NE;       // edge_index[1]

    char* ws = (char*)d_ws;
    size_t off = 0;
    auto alloc = [&](size_t bytes) {
        char* p = ws + off;
        off += (bytes + 255) & ~(size_t)255;
        return p;
    };
    unsigned char*  projT8  = (unsigned char*)alloc((size_t)NN * 128);      // 12.8 MB fp8, f-major
    unsigned short* exb     = (unsigned short*)alloc((size_t)NE * 8 * 2);   // 25.6 MB bf16 ex[e][h]
    unsigned short* s_src_b = (unsigned short*)alloc((size_t)NN * 8 * 2);   // 1.6 MB
    unsigned short* s_tgt_b = (unsigned short*)alloc((size_t)NN * 8 * 2);   // 1.6 MB
    __half*         denom_h = (__half*)alloc((size_t)NN * 8 * 2);           // 1.6 MB f16
    __half*         out_h   = (__half*)alloc((size_t)NN * 16 * 2);          // 3.2 MB f16

    // zero accumulators every call (f16 +0.0 is all-zero bits)
    hipMemsetAsync(denom_h, 0, (size_t)NN * 8 * 2, stream);
    hipMemsetAsync(out_h, 0, (size_t)NN * 16 * 2, stream);

    gemm_score_kernel<<<(NN + 63) / 64, 256, 0, stream>>>(x, W, a_src, a_tgt, projT8,
                                                          s_src_b, s_tgt_b);
    denom_kernel<<<((size_t)NE * 4 + 255) / 256, 256, 0, stream>>>(src, tgt, s_src_b, s_tgt_b,
                                                                   denom_h, exb);
    aggregate_kernel<<<((size_t)NE * 8 + 255) / 256, 256, 0, stream>>>(src, tgt, denom_h, exb,
                                                                       projT8, out_h);
    softmax_kernel<<<(NN * 16 + 255) / 256, 256, 0, stream>>>(out_h, bias, out);
}

// Round 28
// 217.002 us; speedup vs baseline: 1.1043x; 1.1043x over previous
//
#include <hip/hip_runtime.h>
#include <hip/hip_fp16.h>

#define NN 100000
#define NE 1600000
// IN_FEAT=128, N_HEADS=8, OUT_FEAT=16, H*F=128

typedef __attribute__((ext_vector_type(2))) float f32x2;
typedef __attribute__((ext_vector_type(4))) float f32x4;
typedef __attribute__((ext_vector_type(8))) short short8x;   // 8 bf16 (4 VGPRs)

static __device__ __forceinline__ unsigned short f32_to_bf16_rne(float x) {
    unsigned int u = __float_as_uint(x);
    u += 0x7fff + ((u >> 16) & 1);   // round-to-nearest-even
    return (unsigned short)(u >> 16);
}
static __device__ __forceinline__ float bf16_to_f32(unsigned int bits16) {
    return __uint_as_float(bits16 << 16);
}

// ---------------- Kernel 0: prep — W -> bf16 transposed (once) + zero accumulators ----------------
// Blocks 0..15: Wbt[col][k] = bf16(W[k][col])   (32 KB, L2-resident for the whole gemm)
// Blocks 16.. : zero denom_h (1.6 MB) and out_h (3.2 MB) via uint4 grid-stride.
__global__ __launch_bounds__(256) void prep_kernel(const float* __restrict__ W,
                                                   unsigned short* __restrict__ Wbt,
                                                   __half* __restrict__ denom_h,
                                                   __half* __restrict__ out_h) {
    int b = blockIdx.x;
    if (b < 16) {
        int idx = b * 256 + threadIdx.x;      // 0..4095
        int kr = idx >> 5;                    // 0..127
        int c4 = idx & 31;
        float4 v = *reinterpret_cast<const float4*>(&W[(size_t)kr * 128 + c4 * 4]);
        Wbt[(size_t)(c4 * 4 + 0) * 128 + kr] = f32_to_bf16_rne(v.x);
        Wbt[(size_t)(c4 * 4 + 1) * 128 + kr] = f32_to_bf16_rne(v.y);
        Wbt[(size_t)(c4 * 4 + 2) * 128 + kr] = f32_to_bf16_rne(v.z);
        Wbt[(size_t)(c4 * 4 + 3) * 128 + kr] = f32_to_bf16_rne(v.w);
    } else {
        const int total = 300000;             // 100000 (denom) + 200000 (out) uint4 words
        int stride = (gridDim.x - 16) * 256;
        for (int i = (b - 16) * 256 + threadIdx.x; i < total; i += stride) {
            if (i < 100000) reinterpret_cast<uint4*>(denom_h)[i] = make_uint4(0, 0, 0, 0);
            else            reinterpret_cast<uint4*>(out_h)[i - 100000] = make_uint4(0, 0, 0, 0);
        }
    }
}

// ---------------- Kernel 1: MFMA proj-GEMM + attention scores ----------------
// X staged bf16 in LDS; W staged as a raw 32 KB bf16 copy of Wbt (L2-resident, no converts).
// 4 waves x 16 rows; per wave: 8 N-tiles x 4 K-chunks of mfma_f32_16x16x32_bf16.
// C/D layout (m89-verified): col=lane&15, row=(lane>>4)*4+reg.  (r25-proven numerics)
__global__ __launch_bounds__(256) void gemm_score_kernel(const float* __restrict__ x,
                                                         const unsigned short* __restrict__ Wbt,
                                                         const float* __restrict__ a_src,
                                                         const float* __restrict__ a_tgt,
                                                         unsigned char* __restrict__ projT8,
                                                         unsigned short* __restrict__ s_src_b,
                                                         unsigned short* __restrict__ s_tgt_b) {
    __shared__ unsigned short sX[64][136];    // bf16, padded
    __shared__ unsigned short sWT[128][136];  // bf16 copy of Wbt, padded
    const int t = threadIdx.x;
    const int n0 = blockIdx.x * 64;

    // stage x tile (64x128 f32 -> bf16): 2048 float4
#pragma unroll
    for (int p = 0; p < 8; p++) {
        int idx = t + p * 256;          // 0..2047
        int r = idx >> 5;               // 0..63
        int k4 = idx & 31;              // float4 index along k
        float4 v = make_float4(0.f, 0.f, 0.f, 0.f);
        int n = n0 + r;
        if (n < NN) v = *reinterpret_cast<const float4*>(&x[(size_t)n * 128 + k4 * 4]);
        ushort4 bq;
        bq.x = f32_to_bf16_rne(v.x); bq.y = f32_to_bf16_rne(v.y);
        bq.z = f32_to_bf16_rne(v.z); bq.w = f32_to_bf16_rne(v.w);
        *reinterpret_cast<ushort4*>(&sX[r][k4 * 4]) = bq;
    }
    // stage Wbt copy (32 KB): 2048 uint4-of-8-ushort chunks
#pragma unroll
    for (int p = 0; p < 8; p++) {
        int idx = t + p * 256;          // 0..2047
        int r = idx >> 4;               // 0..127 (col)
        int c8 = idx & 15;              // 8-ushort chunk along k
        *reinterpret_cast<uint4*>(&sWT[r][c8 * 8]) =
            *reinterpret_cast<const uint4*>(&Wbt[(size_t)r * 128 + c8 * 8]);
    }
    __syncthreads();

    const int w = t >> 6;       // wave 0..3 -> rows w*16..w*16+15
    const int l = t & 63;
    const int f = l & 15;       // A row / B col within tile; also feature index
    const int kg = l >> 4;      // k-group 0..3

    short8x aF[4];
#pragma unroll
    for (int kc = 0; kc < 4; kc++)
        aF[kc] = *reinterpret_cast<const short8x*>(&sX[w * 16 + f][kc * 32 + kg * 8]);

    f32x4 acc[8];
#pragma unroll
    for (int nt = 0; nt < 8; nt++) acc[nt] = (f32x4){0.f, 0.f, 0.f, 0.f};

#pragma unroll
    for (int kc = 0; kc < 4; kc++) {
#pragma unroll
        for (int nt = 0; nt < 8; nt++) {
            short8x bF = *reinterpret_cast<const short8x*>(&sWT[nt * 16 + f][kc * 32 + kg * 8]);
            acc[nt] = __builtin_amdgcn_mfma_f32_16x16x32_bf16(aF[kc], bF, acc[nt], 0, 0, 0);
        }
    }

    float aS[8], aT[8];
#pragma unroll
    for (int nt = 0; nt < 8; nt++) {
        aS[nt] = a_src[nt * 16 + f];
        aT[nt] = a_tgt[nt * 16 + f];
    }
#pragma unroll
    for (int reg = 0; reg < 4; reg++) {
        int n = n0 + w * 16 + kg * 4 + reg;
        bool valid = (n < NN);
        unsigned int p01 = __builtin_amdgcn_cvt_pk_fp8_f32(acc[0][reg], acc[1][reg], 0, false);
        unsigned int p23 = __builtin_amdgcn_cvt_pk_fp8_f32(acc[2][reg], acc[3][reg], 0, false);
        unsigned int p45 = __builtin_amdgcn_cvt_pk_fp8_f32(acc[4][reg], acc[5][reg], 0, false);
        unsigned int p67 = __builtin_amdgcn_cvt_pk_fp8_f32(acc[6][reg], acc[7][reg], 0, false);
        uint2 st8 = make_uint2((p01 & 0xFFFFu) | (p23 << 16), (p45 & 0xFFFFu) | (p67 << 16));
        if (valid) *reinterpret_cast<uint2*>(&projT8[(size_t)n * 128 + f * 8]) = st8;
#pragma unroll
        for (int nt = 0; nt < 8; nt++) {
            float psS = acc[nt][reg] * aS[nt];
            float psT = acc[nt][reg] * aT[nt];
            psS += __shfl_xor(psS, 1); psS += __shfl_xor(psS, 2);
            psS += __shfl_xor(psS, 4); psS += __shfl_xor(psS, 8);
            psT += __shfl_xor(psT, 1); psT += __shfl_xor(psT, 2);
            psT += __shfl_xor(psT, 4); psT += __shfl_xor(psT, 8);
            if (valid && f == 0) {
                s_src_b[(size_t)n * 8 + nt] = f32_to_bf16_rne(psS);
                s_tgt_b[(size_t)n * 8 + nt] = f32_to_bf16_rne(psT);
            }
        }
    }
}

// ---------------- Kernel 2: denom via packed-f16 HW atomics (frozen from r18/r24) ----------------
__global__ __launch_bounds__(256) void denom_kernel(const int* __restrict__ src,
                                                    const int* __restrict__ tgt,
                                                    const unsigned short* __restrict__ s_src_b,
                                                    const unsigned short* __restrict__ s_tgt_b,
                                                    __half* __restrict__ denom_h,
                                                    unsigned short* __restrict__ exb) {
    int gid = blockIdx.x * blockDim.x + threadIdx.x;
    int e = gid >> 2;
    if (e >= NE) return;
    int h0 = (gid & 3) * 2;
    int s = src[e], t = tgt[e];
    unsigned int ssp = *reinterpret_cast<const unsigned int*>(&s_src_b[(size_t)s * 8 + h0]);
    unsigned int stp = *reinterpret_cast<const unsigned int*>(&s_tgt_b[(size_t)t * 8 + h0]);
    float v0 = bf16_to_f32(ssp & 0xffffu) + bf16_to_f32(stp & 0xffffu);
    float v1 = bf16_to_f32(ssp >> 16) + bf16_to_f32(stp >> 16);
    v0 = v0 >= 0.f ? v0 : 0.2f * v0;
    v1 = v1 >= 0.f ? v1 : 0.2f * v1;
    float ex0 = expf(v0), ex1 = expf(v1);
    unsigned int pk = (unsigned int)f32_to_bf16_rne(ex0) | ((unsigned int)f32_to_bf16_rne(ex1) << 16);
    *reinterpret_cast<unsigned int*>(&exb[(size_t)e * 8 + h0]) = pk;
    unsafeAtomicAdd(reinterpret_cast<__half2*>(&denom_h[(size_t)t * 8 + h0]),
                    __floats2half2_rn(ex0, ex1));
}

// ---------------- Kernel 3: aggregate — fp8 gather + HW fp8 decode (frozen from r24) ----------------
__global__ __launch_bounds__(256) void aggregate_kernel(const int* __restrict__ src,
                                                        const int* __restrict__ tgt,
                                                        const __half* __restrict__ denom_h,
                                                        const unsigned short* __restrict__ exb,
                                                        const unsigned char* __restrict__ projT8,
                                                        __half* __restrict__ out_h) {
    int gid = blockIdx.x * blockDim.x + threadIdx.x;
    int e = gid >> 3;
    if (e >= NE) return;
    int j = gid & 7;       // head j; features 2j, 2j+1
    int s = src[e], t = tgt[e];
    float ex = bf16_to_f32(exb[(size_t)e * 8 + j]);
    float dj = __half2float(denom_h[(size_t)t * 8 + j]);
    float alpha = ex / (dj + 1e-16f);
    uint4 v = *reinterpret_cast<const uint4*>(&projT8[(size_t)s * 128 + j * 16]);
    f32x2 a01 = __builtin_amdgcn_cvt_pk_f32_fp8(v.x, false);
    f32x2 a23 = __builtin_amdgcn_cvt_pk_f32_fp8(v.x, true);
    f32x2 a45 = __builtin_amdgcn_cvt_pk_f32_fp8(v.y, false);
    f32x2 a67 = __builtin_amdgcn_cvt_pk_f32_fp8(v.y, true);
    f32x2 b01 = __builtin_amdgcn_cvt_pk_f32_fp8(v.z, false);
    f32x2 b23 = __builtin_amdgcn_cvt_pk_f32_fp8(v.z, true);
    f32x2 b45 = __builtin_amdgcn_cvt_pk_f32_fp8(v.w, false);
    f32x2 b67 = __builtin_amdgcn_cvt_pk_f32_fp8(v.w, true);
    float pa[8] = {a01.x, a01.y, a23.x, a23.y, a45.x, a45.y, a67.x, a67.y};
    float pb[8] = {b01.x, b01.y, b23.x, b23.y, b45.x, b45.y, b67.x, b67.y};
    float m0 = 0.f, m1 = 0.f;
#pragma unroll
    for (int k = 0; k < 8; k++) {
        float ak = __shfl(alpha, k, 8);
        m0 += ak * pa[k];
        m1 += ak * pb[k];
    }
    unsafeAtomicAdd(reinterpret_cast<__half2*>(&out_h[(size_t)t * 16 + 2 * j]),
                    __floats2half2_rn(m0 * 0.125f, m1 * 0.125f));
}

// ---------------- Kernel 4: bias + softmax over 16 features ----------------
__global__ __launch_bounds__(256) void softmax_kernel(const __half* __restrict__ out_h,
                                                      const float* __restrict__ bias,
                                                      float* __restrict__ out) {
    int gid = blockIdx.x * blockDim.x + threadIdx.x;
    int n = gid >> 4;
    int lane = gid & 15;
    if (n >= NN) return;
    float v = __half2float(out_h[(size_t)n * 16 + lane]) + bias[lane];
    float mx = v;
#pragma unroll
    for (int m = 1; m < 16; m <<= 1) mx = fmaxf(mx, __shfl_xor(mx, m, 64));
    float ex = expf(v - mx);
    float sum = ex;
#pragma unroll
    for (int m = 1; m < 16; m <<= 1) sum += __shfl_xor(sum, m, 64);
    out[(size_t)n * 16 + lane] = ex / sum;
}

extern "C" void kernel_launch(void* const* d_in, const int* in_sizes, int n_in,
                              void* d_out, int out_size, void* d_ws, size_t ws_size,
                              hipStream_t stream) {
    const float* x     = (const float*)d_in[0];
    const int*   ei    = (const int*)d_in[1];
    const float* W     = (const float*)d_in[2];
    const float* a_src = (const float*)d_in[3];
    const float* a_tgt = (const float*)d_in[4];
    const float* bias  = (const float*)d_in[5];
    float* out = (float*)d_out;

    const int* src = ei;            // edge_index[0]
    const int* tgt = ei + NE;       // edge_index[1]

    char* ws = (char*)d_ws;
    size_t off = 0;
    auto alloc = [&](size_t bytes) {
        char* p = ws + off;
        off += (bytes + 255) & ~(size_t)255;
        return p;
    };
    unsigned char*  projT8  = (unsigned char*)alloc((size_t)NN * 128);      // 12.8 MB fp8, f-major
    unsigned short* exb     = (unsigned short*)alloc((size_t)NE * 8 * 2);   // 25.6 MB bf16 ex[e][h]
    unsigned short* s_src_b = (unsigned short*)alloc((size_t)NN * 8 * 2);   // 1.6 MB
    unsigned short* s_tgt_b = (unsigned short*)alloc((size_t)NN * 8 * 2);   // 1.6 MB
    __half*         denom_h = (__half*)alloc((size_t)NN * 8 * 2);           // 1.6 MB f16
    __half*         out_h   = (__half*)alloc((size_t)NN * 16 * 2);          // 3.2 MB f16
    unsigned short* Wbt     = (unsigned short*)alloc((size_t)128 * 128 * 2);// 32 KB bf16 W^T

    prep_kernel<<<1200, 256, 0, stream>>>(W, Wbt, denom_h, out_h);
    gemm_score_kernel<<<(NN + 63) / 64, 256, 0, stream>>>(x, Wbt, a_src, a_tgt, projT8,
                                                          s_src_b, s_tgt_b);
    denom_kernel<<<((size_t)NE * 4 + 255) / 256, 256, 0, stream>>>(src, tgt, s_src_b, s_tgt_b,
                                                                   denom_h, exb);
    aggregate_kernel<<<((size_t)NE * 8 + 255) / 256, 256, 0, stream>>>(src, tgt, denom_h, exb,
                                                                       projT8, out_h);
    softmax_kernel<<<(NN * 16 + 255) / 256, 256, 0, stream>>>(out_h, bias, out);
}